// Round 4
// baseline (589.606 us; speedup 1.0000x reference)
//
#include <hip/hip_runtime.h>
#include <stdint.h>

// ---------------------------------------------------------------------------
// GuidedSegmentTransformer  (B=2, S=512, DIN=256, D=256, H=8, NL=4)
// Inputs: float32. Output: float32. MFMA operands converted to bf16 in ws.
// ---------------------------------------------------------------------------

typedef unsigned short u16;
typedef short  short8  __attribute__((ext_vector_type(8)));
typedef unsigned short ushort8 __attribute__((ext_vector_type(8)));
typedef unsigned int   u32x4   __attribute__((ext_vector_type(4)));
typedef float          f32x4   __attribute__((ext_vector_type(4)));

#define DEV static __device__ __forceinline__

DEV float b2f(u16 u){ union { unsigned int i; float f; } x; x.i = ((unsigned int)u) << 16; return x.f; }
DEV u16  f2b(float f){ union { float f; unsigned int i; } x; x.f = f;
                       unsigned int i = x.i; i += 0x7fffu + ((i >> 16) & 1u); return (u16)(i >> 16); }

DEV float blockSum(float v, float* red, int t){
  #pragma unroll
  for (int m = 32; m; m >>= 1) v += __shfl_xor(v, m, 64);
  __syncthreads();
  if ((t & 63) == 0) red[t >> 6] = v;
  __syncthreads();
  return red[0] + red[1] + red[2] + red[3];
}

// ---------------------------------------------------------------------------
// Convert the 6 MFMA-feeding f32 tensors to bf16 copies in ws.
// ---------------------------------------------------------------------------
struct CvtEnt { const float* src; int dstOff; int n; };
struct CvtTab { CvtEnt e[6]; };

__global__ __launch_bounds__(256) void convert_kernel(CvtTab tab, u16* __restrict__ dst){
  CvtEnt en = tab.e[blockIdx.y];
  int base = blockIdx.x*(256*16) + threadIdx.x;
  #pragma unroll
  for (int i = 0; i < 16; i++){
    int idx = base + i*256;
    if (idx < en.n) dst[en.dstOff + idx] = f2b(en.src[idx]);
  }
}

// ---------------------------------------------------------------------------
// prep: blocks [0,1024) -> sn[row] = sum(x_row^2)  (f32 input);
// blocks [1024,1408) -> W2r[co][k*128+ci] = bf16(c2_w[co][ci][k])
// ---------------------------------------------------------------------------
__global__ __launch_bounds__(256) void prep_kernel(const float* __restrict__ x,
                                                   const float* __restrict__ c2w,
                                                   float* __restrict__ sn,
                                                   u16* __restrict__ W2r){
  __shared__ float red[4];
  int bid = blockIdx.x, t = threadIdx.x;
  if (bid < 1024){
    float v = x[bid*256 + t]; v = v*v;
    float s = blockSum(v, red, t);
    if (t == 0) sn[bid] = s;
  } else {
    int e = (bid - 1024)*256 + t;           // e < 98304
    int co = e / 384, kk = e - co*384;
    int k = kk >> 7, ci = kk & 127;
    W2r[e] = f2b(c2w[co*384 + ci*3 + k]);
  }
}

// ---------------------------------------------------------------------------
// Generic NT MFMA GEMM, BM=BN=64, BK=32, 4 waves (wave w: rows [16w,16w+16)).
// MODE 0 EMBED: C = A@B + bias + pos    -> write f32 + bf16
// MODE 1 QKV  : C = A@B + bias          -> write bf16   (grid.z selects W/b/out)
// MODE 2 PROJ : C = A@B + bias + res    -> write f32
// MODE 3 PW   : B row-major (N x K); C = exp(-max(dist,0)/256) -> bf16
// ---------------------------------------------------------------------------
template<int MODE>
__global__ __launch_bounds__(256) void gemm_nt(
    const u16* __restrict__ A, long long aZ,
    const u16* __restrict__ B0, const u16* __restrict__ B1, const u16* __restrict__ B2, long long bZ,
    const float* __restrict__ bias0, const float* __restrict__ bias1, const float* __restrict__ bias2,
    const float* __restrict__ res, const float* __restrict__ pos,
    const float* __restrict__ sn, long long snZ,
    float* __restrict__ Cf, u16* __restrict__ Cb, long long cZ,
    int M, int N, int K)
{
  __shared__ __align__(16) u16 As[64*40];
  __shared__ __align__(16) u16 Bs[64*40];
  int t = threadIdx.x, w = t >> 6, lane = t & 63, l15 = lane & 15, quad = lane >> 4;
  int m0 = blockIdx.x*64, n0 = blockIdx.y*64, z = blockIdx.z;
  A += (long long)z * aZ;
  const u16* Bp   = (z == 0) ? B0 : ((z == 1) ? B1 : B2);
  Bp += (long long)z * bZ;
  const float* bias = (z == 0) ? bias0 : ((z == 1) ? bias1 : bias2);
  if (Cf) Cf += (long long)z * cZ;
  if (Cb) Cb += (long long)z * cZ;
  const float* snp = sn ? (sn + (long long)z * snZ) : nullptr;

  f32x4 acc[4] = {};
  for (int k0 = 0; k0 < K; k0 += 32){
    { int row = t >> 2, c = (t & 3)*8;        // A tile 64x32, one 16B ld/thread
      *(u32x4*)&As[row*40 + c] = *(const u32x4*)&A[(long long)(m0+row)*K + k0 + c]; }
    if constexpr (MODE == 3){
      int row = t >> 2, c = (t & 3)*8;        // B already (N x K) row-major
      *(u32x4*)&Bs[row*40 + c] = *(const u32x4*)&Bp[(long long)(n0+row)*K + k0 + c];
    } else {                                   // transpose-stage weight (K x N)
      int krow = t >> 3, nc = t & 7;
      ushort8 v = *(const ushort8*)&Bp[(long long)(k0+krow)*N + n0 + nc*8];
      #pragma unroll
      for (int i = 0; i < 8; i++) Bs[(nc*8 + i)*40 + krow] = v[i];
    }
    __syncthreads();
    short8 a = *(const short8*)&As[(w*16 + l15)*40 + quad*8];
    #pragma unroll
    for (int ni = 0; ni < 4; ni++){
      short8 b8 = *(const short8*)&Bs[(ni*16 + l15)*40 + quad*8];
      acc[ni] = __builtin_amdgcn_mfma_f32_16x16x32_bf16(a, b8, acc[ni], 0, 0, 0);
    }
    __syncthreads();
  }
  #pragma unroll
  for (int ni = 0; ni < 4; ni++){
    #pragma unroll
    for (int r = 0; r < 4; r++){
      int row = m0 + w*16 + quad*4 + r;       // D: row = quad*4+reg, col = lane&15
      int col = n0 + ni*16 + l15;
      float v = acc[ni][r];
      if constexpr (MODE == 0){
        v += bias[col] + pos[(row & 511)*N + col];
        Cf[(long long)row*N + col] = v; Cb[(long long)row*N + col] = f2b(v);
      } else if constexpr (MODE == 1){
        v += bias[col]; Cb[(long long)row*N + col] = f2b(v);
      } else if constexpr (MODE == 2){
        v += bias[col] + res[(long long)row*N + col]; Cf[(long long)row*N + col] = v;
      } else {
        float dist = fmaxf(snp[row] + snp[col] - 2.f*v, 0.f);   // >=0 by Cauchy-Schwarz
        Cb[(long long)row*N + col] = f2b(__expf(-dist * (1.f/256.f)));
      }
    }
  }
}

// ---------------------------------------------------------------------------
// Fused conv1(relu) + conv2(relu) + mean-over-L.
// grid (coHalf=2, lchunk=8, n=1024). Per block: GEMM 128co x 64l x 384k.
// ---------------------------------------------------------------------------
__global__ __launch_bounds__(256) void conv_kernel(const u16* __restrict__ pwb,
                                                   const u16* __restrict__ W2r,
                                                   const float* __restrict__ c1w,
                                                   const float* __restrict__ c1b,
                                                   const float* __restrict__ c2b,
                                                   float* __restrict__ x2sum){
  __shared__ __align__(16) u16 Wt[128*40];
  __shared__ __align__(16) u16 Rt[64*40];
  __shared__ float pwrow[68];
  __shared__ float c1wS[128*3];
  __shared__ float c1bS[128];
  int t = threadIdx.x, w = t >> 6, lane = t & 63, l15 = lane & 15, quad = lane >> 4;
  int co0 = blockIdx.x * 128, l0 = blockIdx.y * 64, n = blockIdx.z;

  if (t < 68){ int idx = l0 - 2 + t;
    pwrow[t] = (idx >= 0 && idx < 512) ? b2f(pwb[(long long)n*512 + idx]) : 0.f; }
  if (t < 128){ c1bS[t] = c1b[t];
    #pragma unroll
    for (int j = 0; j < 3; j++) c1wS[t*3 + j] = c1w[t*3 + j]; }
  __syncthreads();

  f32x4 acc[2][4] = {};
  for (int s = 0; s < 12; s++){
    int kq = s >> 2, ci0 = (s & 3) * 32;
    #pragma unroll
    for (int i = 0; i < 2; i++){               // stage W tile 128x32
      int ch = t*2 + i; int row = ch >> 2; int c4 = (ch & 3)*8;
      *(u32x4*)&Wt[row*40 + c4] = *(const u32x4*)&W2r[(long long)(co0+row)*384 + s*32 + c4];
    }
    { // build im2col tile Rt[64 l][32 ci] = relu(conv1) with both paddings
      int c = t & 31, llb = (t >> 5)*8; int ci = ci0 + c;
      float w0 = c1wS[ci*3], w1 = c1wS[ci*3+1], w2c = c1wS[ci*3+2], bb = c1bS[ci];
      #pragma unroll
      for (int i = 0; i < 8; i++){
        int ll = llb + i; int lidx = l0 + ll + kq - 1;
        float v = 0.f;
        if (lidx >= 0 && lidx < 512){
          int p = ll + kq + 1;                  // pwrow index of lidx
          v = fmaxf(w0*pwrow[p-1] + w1*pwrow[p] + w2c*pwrow[p+1] + bb, 0.f);
        }
        Rt[ll*40 + c] = f2b(v);
      }
    }
    __syncthreads();
    short8 a[2];
    #pragma unroll
    for (int mi = 0; mi < 2; mi++) a[mi] = *(const short8*)&Wt[(w*32 + mi*16 + l15)*40 + quad*8];
    #pragma unroll
    for (int nj = 0; nj < 4; nj++){
      short8 b8 = *(const short8*)&Rt[(nj*16 + l15)*40 + quad*8];
      #pragma unroll
      for (int mi = 0; mi < 2; mi++)
        acc[mi][nj] = __builtin_amdgcn_mfma_f32_16x16x32_bf16(a[mi], b8, acc[mi][nj], 0, 0, 0);
    }
    __syncthreads();
  }
  #pragma unroll
  for (int mi = 0; mi < 2; mi++){
    #pragma unroll
    for (int r = 0; r < 4; r++){
      int coL = w*32 + mi*16 + quad*4 + r; int co = co0 + coL;
      float bias = c2b[co];
      float sum = 0.f;
      #pragma unroll
      for (int nj = 0; nj < 4; nj++) sum += fmaxf(acc[mi][nj][r] + bias, 0.f);
      sum += __shfl_xor(sum, 1, 64); sum += __shfl_xor(sum, 2, 64);
      sum += __shfl_xor(sum, 4, 64); sum += __shfl_xor(sum, 8, 64);
      if (l15 == 0) atomicAdd(&x2sum[(long long)n*256 + co], sum * (1.f/512.f));
    }
  }
}

// ---------------------------------------------------------------------------
// Attention: grid (qt=8, h=8, b=2). qtile=64, full K per (b,h) in LDS.
// ---------------------------------------------------------------------------
__global__ __launch_bounds__(256) void attn_kernel(const u16* __restrict__ Qb,
                                                   const u16* __restrict__ Kb,
                                                   const u16* __restrict__ Vb,
                                                   u16* __restrict__ attb){
  __shared__ __align__(16) u16 Qs[64*32];
  __shared__ __align__(16) u16 Ks[512*32];
  __shared__ __align__(16) u16 Ps[64*136];
  __shared__ __align__(16) u16 Vt[32*136];
  int t = threadIdx.x, w = t >> 6, lane = t & 63, l15 = lane & 15, quad = lane >> 4;
  int qt = blockIdx.x, h = blockIdx.y, b = blockIdx.z;
  int row0 = b*512, colh = h*32;

  { int row = t >> 2, c = (t & 3)*8;
    *(u32x4*)&Qs[row*32 + c] = *(const u32x4*)&Qb[(long long)(row0 + qt*64 + row)*256 + colh + c]; }
  #pragma unroll
  for (int i = 0; i < 8; i++){
    int ci = i*256 + t; int row = ci >> 2, c = (ci & 3)*8;
    *(u32x4*)&Ks[row*32 + c] = *(const u32x4*)&Kb[(long long)(row0 + row)*256 + colh + c];
  }
  __syncthreads();

  const f32x4 z4 = {0.f, 0.f, 0.f, 0.f};
  f32x4 sc[32];
  short8 aq = *(const short8*)&Qs[(w*16 + l15)*32 + quad*8];
  #pragma unroll
  for (int kt = 0; kt < 32; kt++){
    short8 bk8 = *(const short8*)&Ks[(kt*16 + l15)*32 + quad*8];
    sc[kt] = __builtin_amdgcn_mfma_f32_16x16x32_bf16(aq, bk8, z4, 0, 0, 0);
  }
  float mx[4] = {-1e30f, -1e30f, -1e30f, -1e30f};
  #pragma unroll
  for (int kt = 0; kt < 32; kt++)
    #pragma unroll
    for (int r = 0; r < 4; r++) mx[r] = fmaxf(mx[r], sc[kt][r]);
  #pragma unroll
  for (int r = 0; r < 4; r++){
    mx[r] = fmaxf(mx[r], __shfl_xor(mx[r], 1, 64));
    mx[r] = fmaxf(mx[r], __shfl_xor(mx[r], 2, 64));
    mx[r] = fmaxf(mx[r], __shfl_xor(mx[r], 4, 64));
    mx[r] = fmaxf(mx[r], __shfl_xor(mx[r], 8, 64));
  }
  float sm[4] = {0.f, 0.f, 0.f, 0.f};
  const float is = 1.f/16.f;                  // scale = sqrt(D) = 16
  #pragma unroll
  for (int kt = 0; kt < 32; kt++)
    #pragma unroll
    for (int r = 0; r < 4; r++){
      float p = __expf(fminf((sc[kt][r] - mx[r]) * is, 0.f));
      sc[kt][r] = p; sm[r] += p;
    }
  #pragma unroll
  for (int r = 0; r < 4; r++){
    sm[r] += __shfl_xor(sm[r], 1, 64); sm[r] += __shfl_xor(sm[r], 2, 64);
    sm[r] += __shfl_xor(sm[r], 4, 64); sm[r] += __shfl_xor(sm[r], 8, 64);
  }
  float inv[4];
  #pragma unroll
  for (int r = 0; r < 4; r++) inv[r] = 1.f / sm[r];

  f32x4 o[2] = {};
  for (int cch = 0; cch < 4; cch++){          // 128-key chunks
    #pragma unroll
    for (int kk = 0; kk < 8; kk++){
      int kt = cch*8 + kk;
      #pragma unroll
      for (int r = 0; r < 4; r++)
        Ps[(w*16 + quad*4 + r)*136 + kk*16 + l15] = f2b(sc[kt][r] * inv[r]);
    }
    #pragma unroll
    for (int i = 0; i < 2; i++){              // stage V^T chunk
      int ci = i*256 + t; int key = ci >> 2; int c = (ci & 3)*8;
      ushort8 v = *(const ushort8*)&Vb[(long long)(row0 + cch*128 + key)*256 + colh + c];
      #pragma unroll
      for (int j = 0; j < 8; j++) Vt[(c + j)*136 + key] = v[j];
    }
    __syncthreads();
    #pragma unroll
    for (int ks = 0; ks < 4; ks++){
      short8 ap = *(const short8*)&Ps[(w*16 + l15)*136 + ks*32 + quad*8];
      #pragma unroll
      for (int ni = 0; ni < 2; ni++){
        short8 bv = *(const short8*)&Vt[(ni*16 + l15)*136 + ks*32 + quad*8];
        o[ni] = __builtin_amdgcn_mfma_f32_16x16x32_bf16(ap, bv, o[ni], 0, 0, 0);
      }
    }
    __syncthreads();
  }
  #pragma unroll
  for (int ni = 0; ni < 2; ni++)
    #pragma unroll
    for (int r = 0; r < 4; r++)
      attb[(long long)(row0 + qt*64 + w*16 + quad*4 + r)*256 + colh + ni*16 + l15] = f2b(o[ni][r]);
}

// ---------------------------------------------------------------------------
__global__ __launch_bounds__(256) void ln_kernel(const float* __restrict__ pre,
                                                 const float* __restrict__ g, const float* __restrict__ bb,
                                                 float* __restrict__ x1f, u16* __restrict__ x1b){
  __shared__ float red[4];
  int row = blockIdx.x, t = threadIdx.x;
  float v = pre[(long long)row*256 + t];
  float mean = blockSum(v, red, t) * (1.f/256.f);
  float d = v - mean;
  float var = blockSum(d*d, red, t) * (1.f/256.f);
  float y = d * rsqrtf(var + 1e-5f) * g[t] + bb[t];
  x1f[(long long)row*256 + t] = y;
  x1b[(long long)row*256 + t] = f2b(y);
}

__global__ __launch_bounds__(256) void pool_kernel(const float* __restrict__ x1f,
                                                   const float* __restrict__ x2sum,
                                                   const float* __restrict__ pos,
                                                   float* __restrict__ hcat){
  int sc = blockIdx.x, b = blockIdx.y, t = threadIdx.x;
  float a1 = 0.f, a2 = 0.f;
  for (int i = 0; i < 64; i++){
    int s = sc*64 + i; long long n = (long long)(b*512 + s);
    a1 += x1f[n*256 + t];
    a2 += x2sum[n*256 + t] + pos[s*256 + t];
  }
  atomicAdd(&hcat[b*512 + t], a1);
  atomicAdd(&hcat[b*512 + 256 + t], a2);
}

__global__ __launch_bounds__(256) void mlp_kernel(const float* __restrict__ hcat,
    const float* __restrict__ h1w, const float* __restrict__ h1b,
    const float* __restrict__ g1,  const float* __restrict__ be1,
    const float* __restrict__ h2w, const float* __restrict__ h2b,
    const float* __restrict__ g2,  const float* __restrict__ be2,
    const float* __restrict__ h3w, const float* __restrict__ h3b,
    float* __restrict__ out){
  __shared__ float hv[512]; __shared__ float z1[256]; __shared__ float z2[128];
  __shared__ float red[4];
  int b = blockIdx.x, t = threadIdx.x;
  hv[t]       = hcat[b*512 + t]       * (1.f/512.f);
  hv[t + 256] = hcat[b*512 + 256 + t] * (1.f/512.f);
  __syncthreads();
  float a = h1b[t];
  for (int k = 0; k < 512; k++) a += hv[k] * h1w[k*256 + t];
  float mean = blockSum(a, red, t) * (1.f/256.f);
  float d = a - mean;
  float var = blockSum(d*d, red, t) * (1.f/256.f);
  float y = d * rsqrtf(var + 1e-5f) * g1[t] + be1[t];
  z1[t] = fmaxf(y, 0.f);
  __syncthreads();
  float a2 = 0.f;
  if (t < 128){ a2 = h2b[t]; for (int k = 0; k < 256; k++) a2 += z1[k] * h2w[k*128 + t]; }
  float mean2 = blockSum(t < 128 ? a2 : 0.f, red, t) * (1.f/128.f);
  float d2 = a2 - mean2;
  float var2 = blockSum(t < 128 ? d2*d2 : 0.f, red, t) * (1.f/128.f);
  if (t < 128) z2[t] = fmaxf(d2 * rsqrtf(var2 + 1e-5f) * g2[t] + be2[t], 0.f);
  __syncthreads();
  float p = (t < 128) ? z2[t] * h3w[t] : 0.f;
  float s = blockSum(p, red, t);
  if (t == 0) out[b] = s + h3b[0];
}

// ---------------------------------------------------------------------------
extern "C" void kernel_launch(void* const* d_in, const int* in_sizes, int n_in,
                              void* d_out, int out_size, void* d_ws, size_t ws_size,
                              hipStream_t stream){
  (void)n_in; (void)out_size; (void)ws_size;
  char* ws = (char*)d_ws;
  float* x1f   = (float*)(ws + 0);         // 1 MB
  float* pre   = (float*)(ws + 1048576);   // 1 MB
  float* x2sum = (float*)(ws + 2097152);   // 1 MB   (memset 0)
  float* hcat  = (float*)(ws + 3145728);   // 4 KB   (memset 0)
  float* sn    = (float*)(ws + 3149824);   // 4 KB
  u16*   x1b   = (u16*) (ws + 3153920);    // 512 KB
  u16*   qkv   = (u16*) (ws + 3678208);    // 1.5 MB (Q,K,V)
  u16*   attb  = (u16*) (ws + 5251072);    // 512 KB
  u16*   pwb   = (u16*) (ws + 5775360);    // 1 MB
  u16*   W2r   = (u16*) (ws + 6823936);    // 192 KB
  u16*   cvt   = (u16*) (ws + 8388608);    // ~2.75 MB bf16 copies of MFMA inputs

  // f32 views of scalar-path inputs
  const float* xF   = (const float*)d_in[0];
  const float* b_in = (const float*)d_in[3];
  const float* pos  = (const float*)d_in[4];
  const float* bq   = (const float*)d_in[9];
  const float* bk   = (const float*)d_in[10];
  const float* bv   = (const float*)d_in[11];
  const float* bo   = (const float*)d_in[12];
  const float* lng  = (const float*)d_in[13];
  const float* lnb  = (const float*)d_in[14];
  const float* c1w  = (const float*)d_in[15];
  const float* c1b  = (const float*)d_in[16];
  const float* c2w  = (const float*)d_in[17];
  const float* c2b  = (const float*)d_in[18];
  const float* h1w  = (const float*)d_in[19];
  const float* h1b  = (const float*)d_in[20];
  const float* g1   = (const float*)d_in[21];
  const float* be1  = (const float*)d_in[22];
  const float* h2w  = (const float*)d_in[23];
  const float* h2b  = (const float*)d_in[24];
  const float* g2   = (const float*)d_in[25];
  const float* be2  = (const float*)d_in[26];
  const float* h3w  = (const float*)d_in[27];
  const float* h3b  = (const float*)d_in[28];

  // bf16 conversion table: x, W_in, Wq, Wk, Wv, Wo
  const int srcIdx[6] = {0, 2, 5, 6, 7, 8};
  CvtTab tab; int off = 0; int maxn = 0; const u16* Pc[6];
  for (int j = 0; j < 6; j++){
    int i = srcIdx[j]; int n = in_sizes[i];
    tab.e[j].src = (const float*)d_in[i]; tab.e[j].dstOff = off; tab.e[j].n = n;
    Pc[j] = cvt + off;
    off += (n + 7) & ~7;
    if (n > maxn) maxn = n;
  }
  const u16 *x = Pc[0], *W_in = Pc[1], *Wq = Pc[2], *Wk = Pc[3], *Wv = Pc[4], *Wo = Pc[5];
  int chunks = (maxn + 256*16 - 1) / (256*16);
  convert_kernel<<<dim3(chunks, 6), 256, 0, stream>>>(tab, cvt);

  hipMemsetAsync(ws + 2097152, 0, 1048576 + 4096, stream);   // x2sum + hcat
  prep_kernel<<<1408, 256, 0, stream>>>(xF, c2w, sn, W2r);
  // x1 = x@W_in + b_in + pos
  gemm_nt<0><<<dim3(16,4,1), 256, 0, stream>>>(x, 0, W_in, W_in, W_in, 0,
      b_in, b_in, b_in, nullptr, pos, nullptr, 0, x1f, x1b, 0, 1024, 256, 256);
  // pw = exp(-dist), per batch (grid.z)
  gemm_nt<3><<<dim3(8,8,2), 256, 0, stream>>>(x, 131072, x, x, x, 131072,
      nullptr, nullptr, nullptr, nullptr, nullptr, sn, 512, nullptr, pwb, 262144, 512, 512, 256);
  // structure branch (dominant compute)
  conv_kernel<<<dim3(2,8,1024), 256, 0, stream>>>(pwb, W2r, c1w, c1b, c2b, x2sum);
  // 4 transformer layers
  for (int L = 0; L < 4; L++){
    gemm_nt<1><<<dim3(16,4,3), 256, 0, stream>>>(x1b, 0,
        Wq + L*65536, Wk + L*65536, Wv + L*65536, 0,
        bq + L*256,  bk + L*256,  bv + L*256,
        nullptr, nullptr, nullptr, 0, nullptr, qkv, 262144, 1024, 256, 256);
    attn_kernel<<<dim3(8,8,2), 256, 0, stream>>>(qkv, qkv + 262144, qkv + 524288, attb);
    gemm_nt<2><<<dim3(16,4,1), 256, 0, stream>>>(attb, 0,
        Wo + L*65536, Wo + L*65536, Wo + L*65536, 0,
        bo + L*256, bo + L*256, bo + L*256,
        x1f, nullptr, nullptr, 0, pre, nullptr, 0, 1024, 256, 256);
    ln_kernel<<<1024, 256, 0, stream>>>(pre, lng + L*256, lnb + L*256, x1f, x1b);
  }
  pool_kernel<<<dim3(8,2,1), 256, 0, stream>>>(x1f, x2sum, pos, hcat);
  mlp_kernel<<<2, 256, 0, stream>>>(hcat, h1w, h1b, g1, be1, h2w, h2b, g2, be2, h3w, h3b,
                                    (float*)d_out);
}

// Round 5
// 506.706 us; speedup vs baseline: 1.1636x; 1.1636x over previous
//
#include <hip/hip_runtime.h>
#include <stdint.h>

// ---------------------------------------------------------------------------
// GuidedSegmentTransformer  (B=2, S=512, DIN=256, D=256, H=8, NL=4)
// Inputs: float32. Output: float32. MFMA operands converted to bf16 in ws.
// ---------------------------------------------------------------------------

typedef unsigned short u16;
typedef short  short8  __attribute__((ext_vector_type(8)));
typedef unsigned short ushort8 __attribute__((ext_vector_type(8)));
typedef unsigned int   u32x4   __attribute__((ext_vector_type(4)));
typedef float          f32x4   __attribute__((ext_vector_type(4)));

#define DEV static __device__ __forceinline__

DEV float b2f(u16 u){ union { unsigned int i; float f; } x; x.i = ((unsigned int)u) << 16; return x.f; }
DEV u16  f2b(float f){ union { float f; unsigned int i; } x; x.f = f;
                       unsigned int i = x.i; i += 0x7fffu + ((i >> 16) & 1u); return (u16)(i >> 16); }

DEV float blockSum(float v, float* red, int t){
  #pragma unroll
  for (int m = 32; m; m >>= 1) v += __shfl_xor(v, m, 64);
  __syncthreads();
  if ((t & 63) == 0) red[t >> 6] = v;
  __syncthreads();
  return red[0] + red[1] + red[2] + red[3];
}

// ---------------------------------------------------------------------------
// Convert the 6 MFMA-feeding f32 tensors to bf16 copies in ws.
// ---------------------------------------------------------------------------
struct CvtEnt { const float* src; int dstOff; int n; };
struct CvtTab { CvtEnt e[6]; };

__global__ __launch_bounds__(256) void convert_kernel(CvtTab tab, u16* __restrict__ dst){
  CvtEnt en = tab.e[blockIdx.y];
  int base = blockIdx.x*(256*16) + threadIdx.x;
  #pragma unroll
  for (int i = 0; i < 16; i++){
    int idx = base + i*256;
    if (idx < en.n) dst[en.dstOff + idx] = f2b(en.src[idx]);
  }
}

// ---------------------------------------------------------------------------
// prep: blocks [0,1024) -> sn[row]; blocks [1024,1408) -> W2r reorder (bf16)
// ---------------------------------------------------------------------------
__global__ __launch_bounds__(256) void prep_kernel(const float* __restrict__ x,
                                                   const float* __restrict__ c2w,
                                                   float* __restrict__ sn,
                                                   u16* __restrict__ W2r){
  __shared__ float red[4];
  int bid = blockIdx.x, t = threadIdx.x;
  if (bid < 1024){
    float v = x[bid*256 + t]; v = v*v;
    float s = blockSum(v, red, t);
    if (t == 0) sn[bid] = s;
  } else {
    int e = (bid - 1024)*256 + t;
    int co = e / 384, kk = e - co*384;
    int k = kk >> 7, ci = kk & 127;
    W2r[e] = f2b(c2w[co*384 + ci*3 + k]);
  }
}

// ---------------------------------------------------------------------------
// Generic NT MFMA GEMM, BM=BN=64, BK=32.
// MODE 0 EMBED: C = A@B + bias + pos -> f32 + bf16
// MODE 1 QKV  : C = A@B + bias       -> bf16 (grid.z selects W/b/out)
// MODE 3 PW   : B row-major (N x K); C = exp(-max(dist,0)/256) -> bf16
// ---------------------------------------------------------------------------
template<int MODE>
__global__ __launch_bounds__(256) void gemm_nt(
    const u16* __restrict__ A, long long aZ,
    const u16* __restrict__ B0, const u16* __restrict__ B1, const u16* __restrict__ B2, long long bZ,
    const float* __restrict__ bias0, const float* __restrict__ bias1, const float* __restrict__ bias2,
    const float* __restrict__ pos,
    const float* __restrict__ sn, long long snZ,
    float* __restrict__ Cf, u16* __restrict__ Cb, long long cZ,
    int M, int N, int K)
{
  __shared__ __align__(16) u16 As[64*40];
  __shared__ __align__(16) u16 Bs[64*40];
  int t = threadIdx.x, w = t >> 6, lane = t & 63, l15 = lane & 15, quad = lane >> 4;
  int m0 = blockIdx.x*64, n0 = blockIdx.y*64, z = blockIdx.z;
  A += (long long)z * aZ;
  const u16* Bp   = (z == 0) ? B0 : ((z == 1) ? B1 : B2);
  Bp += (long long)z * bZ;
  const float* bias = (z == 0) ? bias0 : ((z == 1) ? bias1 : bias2);
  if (Cf) Cf += (long long)z * cZ;
  if (Cb) Cb += (long long)z * cZ;
  const float* snp = sn ? (sn + (long long)z * snZ) : nullptr;

  f32x4 acc[4] = {};
  for (int k0 = 0; k0 < K; k0 += 32){
    { int row = t >> 2, c = (t & 3)*8;
      *(u32x4*)&As[row*40 + c] = *(const u32x4*)&A[(long long)(m0+row)*K + k0 + c]; }
    if constexpr (MODE == 3){
      int row = t >> 2, c = (t & 3)*8;
      *(u32x4*)&Bs[row*40 + c] = *(const u32x4*)&Bp[(long long)(n0+row)*K + k0 + c];
    } else {
      int krow = t >> 3, nc = t & 7;
      ushort8 v = *(const ushort8*)&Bp[(long long)(k0+krow)*N + n0 + nc*8];
      #pragma unroll
      for (int i = 0; i < 8; i++) Bs[(nc*8 + i)*40 + krow] = v[i];
    }
    __syncthreads();
    short8 a = *(const short8*)&As[(w*16 + l15)*40 + quad*8];
    #pragma unroll
    for (int ni = 0; ni < 4; ni++){
      short8 b8 = *(const short8*)&Bs[(ni*16 + l15)*40 + quad*8];
      acc[ni] = __builtin_amdgcn_mfma_f32_16x16x32_bf16(a, b8, acc[ni], 0, 0, 0);
    }
    __syncthreads();
  }
  #pragma unroll
  for (int ni = 0; ni < 4; ni++){
    #pragma unroll
    for (int r = 0; r < 4; r++){
      int row = m0 + w*16 + quad*4 + r;
      int col = n0 + ni*16 + l15;
      float v = acc[ni][r];
      if constexpr (MODE == 0){
        v += bias[col] + pos[(row & 511)*N + col];
        Cf[(long long)row*N + col] = v; Cb[(long long)row*N + col] = f2b(v);
      } else if constexpr (MODE == 1){
        v += bias[col]; Cb[(long long)row*N + col] = f2b(v);
      } else {
        float dist = fmaxf(snp[row] + snp[col] - 2.f*v, 0.f);
        Cb[(long long)row*N + col] = f2b(__expf(-dist * (1.f/256.f)));
      }
    }
  }
}

// ---------------------------------------------------------------------------
// Fused conv1(relu)+conv2(relu)+mean. grid (2 co-halves, 1024 n).
// Per block: im2col r1t once per 64-l chunk; weights register-resident;
// relu+mean accumulated in registers; single store (no atomics).
// ---------------------------------------------------------------------------
__global__ __launch_bounds__(256) void conv_kernel(const u16* __restrict__ pwb,
                                                   const u16* __restrict__ W2r,
                                                   const float* __restrict__ c1w,
                                                   const float* __restrict__ c1b,
                                                   const float* __restrict__ c2b,
                                                   float* __restrict__ x2sum){
  __shared__ __align__(16) u16 r1t[66*136];   // [g][ci], g = l-l0+1 (halo)
  __shared__ float pwAll[520];                 // pw row with 2-halo each side
  int t = threadIdx.x, w = t >> 6, lane = t & 63, l15 = lane & 15, quad = lane >> 4;
  int co0 = blockIdx.x*128, n = blockIdx.y;

  for (int i = t; i < 516; i += 256){
    int l = i - 2;
    pwAll[i] = ((unsigned)l < 512u) ? b2f(pwb[(long long)n*512 + l]) : 0.f;
  }
  int ci = t & 127, half = t >> 7;
  float w0 = c1w[ci*3], w1 = c1w[ci*3+1], w2 = c1w[ci*3+2], cb = c1b[ci];

  // register-resident A fragments: wave w covers co rows [co0+32w, co0+32w+32)
  short8 aF[12][2];
  #pragma unroll
  for (int s = 0; s < 12; s++)
    #pragma unroll
    for (int mi = 0; mi < 2; mi++)
      aF[s][mi] = *(const short8*)&W2r[(co0 + w*32 + mi*16 + l15)*384 + s*32 + quad*8];

  float bias[2][4], accsum[2][4] = {};
  #pragma unroll
  for (int mi = 0; mi < 2; mi++)
    #pragma unroll
    for (int r = 0; r < 4; r++) bias[mi][r] = c2b[co0 + w*32 + mi*16 + quad*4 + r];

  for (int chunk = 0; chunk < 8; chunk++){
    int l0 = chunk*64;
    __syncthreads();                          // prev chunk's reads done / pwAll ready
    #pragma unroll
    for (int j = 0; j < 33; j++){
      int g = half + 2*j;                     // half0: 0..64, half1: 1..65
      int lidx = l0 - 1 + g;
      float v = fmaxf(w0*pwAll[lidx+1] + w1*pwAll[lidx+2] + w2*pwAll[lidx+3] + cb, 0.f);
      v = ((unsigned)lidx < 512u) ? v : 0.f;
      r1t[g*136 + ci] = f2b(v);
    }
    __syncthreads();
    f32x4 acc[2][4] = {};
    #pragma unroll
    for (int s = 0; s < 12; s++){
      int kq = s >> 2, ci0 = (s & 3)*32;
      #pragma unroll
      for (int nj = 0; nj < 4; nj++){
        short8 b8 = *(const short8*)&r1t[(nj*16 + l15 + kq)*136 + ci0 + quad*8];
        acc[0][nj] = __builtin_amdgcn_mfma_f32_16x16x32_bf16(aF[s][0], b8, acc[0][nj], 0, 0, 0);
        acc[1][nj] = __builtin_amdgcn_mfma_f32_16x16x32_bf16(aF[s][1], b8, acc[1][nj], 0, 0, 0);
      }
    }
    #pragma unroll
    for (int mi = 0; mi < 2; mi++)
      #pragma unroll
      for (int r = 0; r < 4; r++){
        float s4 = 0.f;
        #pragma unroll
        for (int nj = 0; nj < 4; nj++) s4 += fmaxf(acc[mi][nj][r] + bias[mi][r], 0.f);
        accsum[mi][r] += s4;
      }
  }
  #pragma unroll
  for (int mi = 0; mi < 2; mi++)
    #pragma unroll
    for (int r = 0; r < 4; r++){
      float s = accsum[mi][r];
      s += __shfl_xor(s, 1, 64); s += __shfl_xor(s, 2, 64);
      s += __shfl_xor(s, 4, 64); s += __shfl_xor(s, 8, 64);
      if (l15 == 0)
        x2sum[(long long)n*256 + co0 + w*32 + mi*16 + quad*4 + r] = s * (1.f/512.f);
    }
}

// ---------------------------------------------------------------------------
// Attention: grid (qt=8, h=8, b=2).
// ---------------------------------------------------------------------------
__global__ __launch_bounds__(256) void attn_kernel(const u16* __restrict__ Qb,
                                                   const u16* __restrict__ Kb,
                                                   const u16* __restrict__ Vb,
                                                   u16* __restrict__ attb){
  __shared__ __align__(16) u16 Qs[64*32];
  __shared__ __align__(16) u16 Ks[512*32];
  __shared__ __align__(16) u16 Ps[64*136];
  __shared__ __align__(16) u16 Vt[32*136];
  int t = threadIdx.x, w = t >> 6, lane = t & 63, l15 = lane & 15, quad = lane >> 4;
  int qt = blockIdx.x, h = blockIdx.y, b = blockIdx.z;
  int row0 = b*512, colh = h*32;

  { int row = t >> 2, c = (t & 3)*8;
    *(u32x4*)&Qs[row*32 + c] = *(const u32x4*)&Qb[(long long)(row0 + qt*64 + row)*256 + colh + c]; }
  #pragma unroll
  for (int i = 0; i < 8; i++){
    int ci = i*256 + t; int row = ci >> 2, c = (ci & 3)*8;
    *(u32x4*)&Ks[row*32 + c] = *(const u32x4*)&Kb[(long long)(row0 + row)*256 + colh + c];
  }
  __syncthreads();

  const f32x4 z4 = {0.f, 0.f, 0.f, 0.f};
  f32x4 sc[32];
  short8 aq = *(const short8*)&Qs[(w*16 + l15)*32 + quad*8];
  #pragma unroll
  for (int kt = 0; kt < 32; kt++){
    short8 bk8 = *(const short8*)&Ks[(kt*16 + l15)*32 + quad*8];
    sc[kt] = __builtin_amdgcn_mfma_f32_16x16x32_bf16(aq, bk8, z4, 0, 0, 0);
  }
  float mx[4] = {-1e30f, -1e30f, -1e30f, -1e30f};
  #pragma unroll
  for (int kt = 0; kt < 32; kt++)
    #pragma unroll
    for (int r = 0; r < 4; r++) mx[r] = fmaxf(mx[r], sc[kt][r]);
  #pragma unroll
  for (int r = 0; r < 4; r++){
    mx[r] = fmaxf(mx[r], __shfl_xor(mx[r], 1, 64));
    mx[r] = fmaxf(mx[r], __shfl_xor(mx[r], 2, 64));
    mx[r] = fmaxf(mx[r], __shfl_xor(mx[r], 4, 64));
    mx[r] = fmaxf(mx[r], __shfl_xor(mx[r], 8, 64));
  }
  float sm[4] = {0.f, 0.f, 0.f, 0.f};
  const float is = 1.f/16.f;
  #pragma unroll
  for (int kt = 0; kt < 32; kt++)
    #pragma unroll
    for (int r = 0; r < 4; r++){
      float p = __expf(fminf((sc[kt][r] - mx[r]) * is, 0.f));
      sc[kt][r] = p; sm[r] += p;
    }
  #pragma unroll
  for (int r = 0; r < 4; r++){
    sm[r] += __shfl_xor(sm[r], 1, 64); sm[r] += __shfl_xor(sm[r], 2, 64);
    sm[r] += __shfl_xor(sm[r], 4, 64); sm[r] += __shfl_xor(sm[r], 8, 64);
  }
  float inv[4];
  #pragma unroll
  for (int r = 0; r < 4; r++) inv[r] = 1.f / sm[r];

  f32x4 o[2] = {};
  for (int cch = 0; cch < 4; cch++){
    #pragma unroll
    for (int kk = 0; kk < 8; kk++){
      int kt = cch*8 + kk;
      #pragma unroll
      for (int r = 0; r < 4; r++)
        Ps[(w*16 + quad*4 + r)*136 + kk*16 + l15] = f2b(sc[kt][r] * inv[r]);
    }
    #pragma unroll
    for (int i = 0; i < 2; i++){
      int ci = i*256 + t; int key = ci >> 2; int c = (ci & 3)*8;
      ushort8 v = *(const ushort8*)&Vb[(long long)(row0 + cch*128 + key)*256 + colh + c];
      #pragma unroll
      for (int j = 0; j < 8; j++) Vt[(c + j)*136 + key] = v[j];
    }
    __syncthreads();
    #pragma unroll
    for (int ks = 0; ks < 4; ks++){
      short8 ap = *(const short8*)&Ps[(w*16 + l15)*136 + ks*32 + quad*8];
      #pragma unroll
      for (int ni = 0; ni < 2; ni++){
        short8 bv = *(const short8*)&Vt[(ni*16 + l15)*136 + ks*32 + quad*8];
        o[ni] = __builtin_amdgcn_mfma_f32_16x16x32_bf16(ap, bv, o[ni], 0, 0, 0);
      }
    }
    __syncthreads();
  }
  #pragma unroll
  for (int ni = 0; ni < 2; ni++)
    #pragma unroll
    for (int r = 0; r < 4; r++)
      attb[(long long)(row0 + qt*64 + w*16 + quad*4 + r)*256 + colh + ni*16 + l15] = f2b(o[ni][r]);
}

// ---------------------------------------------------------------------------
// Fused proj GEMM + bias + residual + LayerNorm. BM=64, BN=256 (full rows).
// grid 16 blocks. Writes x1f (f32) and x1b (bf16).
// ---------------------------------------------------------------------------
__global__ __launch_bounds__(256) void projln_kernel(const u16* __restrict__ A,
    const u16* __restrict__ Wo, const float* __restrict__ bo,
    const float* __restrict__ lng, const float* __restrict__ lnb,
    float* __restrict__ x1f, u16* __restrict__ x1b){
  __shared__ __align__(16) u16 As[64*40];
  __shared__ __align__(16) u16 Bs[256*40];
  int t = threadIdx.x, w = t >> 6, lane = t & 63, l15 = lane & 15, quad = lane >> 4;
  int m0 = blockIdx.x*64;

  f32x4 acc[16] = {};
  for (int k0 = 0; k0 < 256; k0 += 32){
    { int row = t >> 2, c = (t & 3)*8;
      *(u32x4*)&As[row*40 + c] = *(const u32x4*)&A[(long long)(m0+row)*256 + k0 + c]; }
    #pragma unroll
    for (int it = 0; it < 4; it++){
      int krow = (t >> 5) + it*8, nc = t & 31;
      ushort8 v = *(const ushort8*)&Wo[(long long)(k0+krow)*256 + nc*8];
      #pragma unroll
      for (int i = 0; i < 8; i++) Bs[(nc*8 + i)*40 + krow] = v[i];
    }
    __syncthreads();
    short8 a = *(const short8*)&As[(w*16 + l15)*40 + quad*8];
    #pragma unroll
    for (int nj = 0; nj < 16; nj++){
      short8 b8 = *(const short8*)&Bs[(nj*16 + l15)*40 + quad*8];
      acc[nj] = __builtin_amdgcn_mfma_f32_16x16x32_bf16(a, b8, acc[nj], 0, 0, 0);
    }
    __syncthreads();
  }
  #pragma unroll
  for (int r = 0; r < 4; r++){
    int row = m0 + w*16 + quad*4 + r;
    float vv[16]; float s1 = 0.f;
    #pragma unroll
    for (int nj = 0; nj < 16; nj++){
      int col = nj*16 + l15;
      float v = acc[nj][r] + bo[col] + x1f[(long long)row*256 + col];
      vv[nj] = v; s1 += v;
    }
    s1 += __shfl_xor(s1, 1, 64); s1 += __shfl_xor(s1, 2, 64);
    s1 += __shfl_xor(s1, 4, 64); s1 += __shfl_xor(s1, 8, 64);
    float mean = s1 * (1.f/256.f);
    float s2 = 0.f;
    #pragma unroll
    for (int nj = 0; nj < 16; nj++){ float d = vv[nj] - mean; s2 += d*d; }
    s2 += __shfl_xor(s2, 1, 64); s2 += __shfl_xor(s2, 2, 64);
    s2 += __shfl_xor(s2, 4, 64); s2 += __shfl_xor(s2, 8, 64);
    float rs = rsqrtf(s2 * (1.f/256.f) + 1e-5f);
    #pragma unroll
    for (int nj = 0; nj < 16; nj++){
      int col = nj*16 + l15;
      float y = (vv[nj] - mean) * rs * lng[col] + lnb[col];
      x1f[(long long)row*256 + col] = y;
      x1b[(long long)row*256 + col] = f2b(y);
    }
  }
}

// ---------------------------------------------------------------------------
__global__ __launch_bounds__(256) void pool_kernel(const float* __restrict__ x1f,
                                                   const float* __restrict__ x2sum,
                                                   const float* __restrict__ pos,
                                                   float* __restrict__ hcat){
  int sc = blockIdx.x, b = blockIdx.y, t = threadIdx.x;
  float a1 = 0.f, a2 = 0.f;
  for (int i = 0; i < 64; i++){
    int s = sc*64 + i; long long n = (long long)(b*512 + s);
    a1 += x1f[n*256 + t];
    a2 += x2sum[n*256 + t] + pos[s*256 + t];
  }
  atomicAdd(&hcat[b*512 + t], a1);
  atomicAdd(&hcat[b*512 + 256 + t], a2);
}

__global__ __launch_bounds__(256) void mlp_kernel(const float* __restrict__ hcat,
    const float* __restrict__ h1w, const float* __restrict__ h1b,
    const float* __restrict__ g1,  const float* __restrict__ be1,
    const float* __restrict__ h2w, const float* __restrict__ h2b,
    const float* __restrict__ g2,  const float* __restrict__ be2,
    const float* __restrict__ h3w, const float* __restrict__ h3b,
    float* __restrict__ out){
  __shared__ float hv[512]; __shared__ float z1[256]; __shared__ float z2[128];
  __shared__ float red[4];
  int b = blockIdx.x, t = threadIdx.x;
  hv[t]       = hcat[b*512 + t]       * (1.f/512.f);
  hv[t + 256] = hcat[b*512 + 256 + t] * (1.f/512.f);
  __syncthreads();
  float a = h1b[t];
  for (int k = 0; k < 512; k++) a += hv[k] * h1w[k*256 + t];
  float mean = blockSum(a, red, t) * (1.f/256.f);
  float d = a - mean;
  float var = blockSum(d*d, red, t) * (1.f/256.f);
  float y = d * rsqrtf(var + 1e-5f) * g1[t] + be1[t];
  z1[t] = fmaxf(y, 0.f);
  __syncthreads();
  float a2 = 0.f;
  if (t < 128){ a2 = h2b[t]; for (int k = 0; k < 256; k++) a2 += z1[k] * h2w[k*128 + t]; }
  float mean2 = blockSum(t < 128 ? a2 : 0.f, red, t) * (1.f/128.f);
  float d2 = a2 - mean2;
  float var2 = blockSum(t < 128 ? d2*d2 : 0.f, red, t) * (1.f/128.f);
  if (t < 128) z2[t] = fmaxf(d2 * rsqrtf(var2 + 1e-5f) * g2[t] + be2[t], 0.f);
  __syncthreads();
  float p = (t < 128) ? z2[t] * h3w[t] : 0.f;
  float s = blockSum(p, red, t);
  if (t == 0) out[b] = s + h3b[0];
}

// ---------------------------------------------------------------------------
extern "C" void kernel_launch(void* const* d_in, const int* in_sizes, int n_in,
                              void* d_out, int out_size, void* d_ws, size_t ws_size,
                              hipStream_t stream){
  (void)n_in; (void)out_size; (void)ws_size;
  char* ws = (char*)d_ws;
  float* x1f   = (float*)(ws + 0);         // 1 MB
  float* x2sum = (float*)(ws + 2097152);   // 1 MB
  float* hcat  = (float*)(ws + 3145728);   // 4 KB (memset 0)
  float* sn    = (float*)(ws + 3149824);   // 4 KB
  u16*   x1b   = (u16*) (ws + 3153920);    // 512 KB
  u16*   qkv   = (u16*) (ws + 3678208);    // 1.5 MB (Q,K,V)
  u16*   attb  = (u16*) (ws + 5251072);    // 512 KB
  u16*   pwb   = (u16*) (ws + 5775360);    // 1 MB
  u16*   W2r   = (u16*) (ws + 6823936);    // 192 KB
  u16*   cvt   = (u16*) (ws + 8388608);    // ~2.75 MB bf16 copies

  const float* xF   = (const float*)d_in[0];
  const float* b_in = (const float*)d_in[3];
  const float* pos  = (const float*)d_in[4];
  const float* bq   = (const float*)d_in[9];
  const float* bk   = (const float*)d_in[10];
  const float* bv   = (const float*)d_in[11];
  const float* bo   = (const float*)d_in[12];
  const float* lng  = (const float*)d_in[13];
  const float* lnb  = (const float*)d_in[14];
  const float* c1w  = (const float*)d_in[15];
  const float* c1b  = (const float*)d_in[16];
  const float* c2w  = (const float*)d_in[17];
  const float* c2b  = (const float*)d_in[18];
  const float* h1w  = (const float*)d_in[19];
  const float* h1b  = (const float*)d_in[20];
  const float* g1   = (const float*)d_in[21];
  const float* be1  = (const float*)d_in[22];
  const float* h2w  = (const float*)d_in[23];
  const float* h2b  = (const float*)d_in[24];
  const float* g2   = (const float*)d_in[25];
  const float* be2  = (const float*)d_in[26];
  const float* h3w  = (const float*)d_in[27];
  const float* h3b  = (const float*)d_in[28];

  const int srcIdx[6] = {0, 2, 5, 6, 7, 8};
  CvtTab tab; int off = 0; int maxn = 0; const u16* Pc[6];
  for (int j = 0; j < 6; j++){
    int i = srcIdx[j]; int n = in_sizes[i];
    tab.e[j].src = (const float*)d_in[i]; tab.e[j].dstOff = off; tab.e[j].n = n;
    Pc[j] = cvt + off;
    off += (n + 7) & ~7;
    if (n > maxn) maxn = n;
  }
  const u16 *x = Pc[0], *W_in = Pc[1], *Wq = Pc[2], *Wk = Pc[3], *Wv = Pc[4], *Wo = Pc[5];
  int chunks = (maxn + 256*16 - 1) / (256*16);
  convert_kernel<<<dim3(chunks, 6), 256, 0, stream>>>(tab, cvt);

  hipMemsetAsync(hcat, 0, 4096, stream);
  prep_kernel<<<1408, 256, 0, stream>>>(xF, c2w, sn, W2r);
  gemm_nt<0><<<dim3(16,4,1), 256, 0, stream>>>(x, 0, W_in, W_in, W_in, 0,
      b_in, b_in, b_in, pos, nullptr, 0, x1f, x1b, 0, 1024, 256, 256);
  gemm_nt<3><<<dim3(8,8,2), 256, 0, stream>>>(x, 131072, x, x, x, 131072,
      nullptr, nullptr, nullptr, nullptr, sn, 512, nullptr, pwb, 262144, 512, 512, 256);
  conv_kernel<<<dim3(2,1024), 256, 0, stream>>>(pwb, W2r, c1w, c1b, c2b, x2sum);
  for (int L = 0; L < 4; L++){
    gemm_nt<1><<<dim3(16,4,3), 256, 0, stream>>>(x1b, 0,
        Wq + L*65536, Wk + L*65536, Wv + L*65536, 0,
        bq + L*256,  bk + L*256,  bv + L*256,
        nullptr, nullptr, 0, nullptr, qkv, 262144, 1024, 256, 256);
    attn_kernel<<<dim3(8,8,2), 256, 0, stream>>>(qkv, qkv + 262144, qkv + 524288, attb);
    projln_kernel<<<16, 256, 0, stream>>>(attb, Wo + L*65536, bo + L*256,
        lng + L*256, lnb + L*256, x1f, x1b);
  }
  pool_kernel<<<dim3(8,2,1), 256, 0, stream>>>(x1f, x2sum, pos, hcat);
  mlp_kernel<<<2, 256, 0, stream>>>(hcat, h1w, h1b, g1, be1, h2w, h2b, g2, be2, h3w, h3b,
                                    (float*)d_out);
}